// Round 2
// baseline (178.524 us; speedup 1.0000x reference)
//
#include <hip/hip_runtime.h>
#include <math.h>

// DP-GCN constants (EPS=1, ALPHA=0.5, DELTA=1):
//   transformed = ((e+1)*x - 1) * (1/(e-1)) + 0.5 = C1*x + C0
#define C1 2.163953413738653f
#define C0 -0.081976706869326f

// NOTE: assumes N <= 65536 so node ids fit u16 (N=50000 here).

typedef __attribute__((ext_vector_type(8))) short bf16x8;
typedef __attribute__((ext_vector_type(4))) float f32x4;

static __device__ __forceinline__ unsigned short f2bf(float f) {   // RTN-even
    unsigned b = __float_as_uint(f);
    return (unsigned short)((b + 0x7FFFu + ((b >> 16) & 1u)) >> 16);
}
static __device__ __forceinline__ float bf2f(unsigned short u) {
    return __uint_as_float((unsigned)u << 16);
}
// unpack a u32 holding two bf16 (little-endian: low half = even dim)
static __device__ __forceinline__ float bfl(unsigned u) { return __uint_as_float(u << 16); }
static __device__ __forceinline__ float bfh(unsigned u) { return __uint_as_float(u & 0xFFFF0000u); }

// ---- col-digit histogram + global-atomic deg; blocks 0/1 also convert W1/W2
// to bf16 swizzled into MFMA B-fragment order. hist[d*256+b] col-digit counts.
// chunk is a multiple of 4 so &row[lo] is 16B-aligned for int4 loads.
__global__ __launch_bounds__(1024) void k_hist2(const int* __restrict__ row,
                                                const int* __restrict__ col, int E, int chunk,
                                                int* __restrict__ hist, int* __restrict__ deg,
                                                const float* __restrict__ W1,
                                                const float* __restrict__ W2,
                                                unsigned short* __restrict__ W1b,
                                                unsigned short* __restrict__ W2b) {
    __shared__ int hc[256];
    int t = threadIdx.x, b = blockIdx.x;
    if (t < 256) hc[t] = 0;
    __syncthreads();
    int lo = b * chunk, hi = min(E, lo + chunk);
    int base = lo + t * 4;
    for (; base + 3 < hi; base += 4096) {
        int4 r4 = *(const int4*)&row[base];
        int4 c4 = *(const int4*)&col[base];
        atomicAdd(&hc[c4.x >> 8], 1); atomicAdd(&hc[c4.y >> 8], 1);
        atomicAdd(&hc[c4.z >> 8], 1); atomicAdd(&hc[c4.w >> 8], 1);
        atomicAdd(&deg[r4.x], 1); atomicAdd(&deg[r4.y], 1);
        atomicAdd(&deg[r4.z], 1); atomicAdd(&deg[r4.w], 1);
    }
    for (; base < hi; ++base) {
        atomicAdd(&hc[col[base] >> 8], 1);
        atomicAdd(&deg[row[base]], 1);
    }
    __syncthreads();
    if (t < 256) hist[t * 256 + b] = hc[t];
    // B-fragment swizzle: frag element j of lane l for (ntile, ktile) holds
    // B[k = kt*32 + (l>>4)*8 + j][n = nt*16 + (l&15)], stored contiguously.
    if (b == 0) {
        for (int i = t; i < 8192; i += 1024) {           // W1: 8 nt x 2 kt
            int j = i & 7, l2 = (i >> 3) & 63, kt = (i >> 9) & 1, nt = i >> 10;
            int k = kt * 32 + (l2 >> 4) * 8 + j, n = nt * 16 + (l2 & 15);
            W1b[i] = f2bf(W1[k * 128 + n]);
        }
    } else if (b == 1) {
        for (int i = t; i < 4096; i += 1024) {           // W2: 2 nt x 4 kt
            int j = i & 7, l2 = (i >> 3) & 63, kt = (i >> 9) & 3, nt = i >> 11;
            int k = kt * 32 + (l2 >> 4) * 8 + j, n = nt * 16 + (l2 & 15);
            W2b[i] = f2bf(W2[k * 32 + n]);
        }
    }
}

// ---- blocks [0,256): level-1 exclusive scan of col-digit counts.
//      excl[d*256+b] = within-digit prefix over blocks<b; bsum[d] = digit total.
// ---- blocks [256,256+nbk): dis = rsqrt(deg+1); xt = bf16(dis * transform(x)).
__global__ __launch_bounds__(256) void k_scan2(const int* __restrict__ cnt,
                                               int* __restrict__ excl,
                                               int* __restrict__ bsum, int n,
                                               const int* __restrict__ deg,
                                               const int* __restrict__ priv,
                                               const float* __restrict__ x, int N,
                                               float* __restrict__ dis,
                                               unsigned short* __restrict__ xt) {
    __shared__ int s[256];
    __shared__ float sdv[256];
    __shared__ int sp[256];
    int t = threadIdx.x;
    if ((int)blockIdx.x < 256) {
        int idx = blockIdx.x * 256 + t;
        int v = (idx < n) ? cnt[idx] : 0;
        s[t] = v;
        __syncthreads();
        for (int off = 1; off < 256; off <<= 1) {
            int u = (t >= off) ? s[t - off] : 0;
            __syncthreads();
            s[t] += u;
            __syncthreads();
        }
        if (idx < n) excl[idx] = s[t] - v;
        if (t == 255) bsum[blockIdx.x] = s[255];
    } else {
        int b2 = blockIdx.x - 256;
        int node = b2 * 256 + t;
        float dv = 0.f;
        int p = 0;
        if (node < N) {
            dv = rsqrtf((float)(deg[node] + 1));   // +1 self loop
            dis[node] = dv;
            p = priv[node];
        }
        sdv[t] = dv;
        sp[t] = p;
        __syncthreads();
        int basen = b2 * 256;
        for (int i = t; i < 256 * 16; i += 256) {    // 16 float4 per node
            int ln = i >> 4;
            int n2 = basen + ln;
            if (n2 >= N) continue;
            float d2 = sdv[ln];
            int pp = sp[ln];
            float4 v = ((const float4*)x)[(size_t)n2 * 16 + (i & 15)];
            float4 tr;
            tr.x = pp ? fmaf(C1, v.x, C0) : v.x;
            tr.y = pp ? fmaf(C1, v.y, C0) : v.y;
            tr.z = pp ? fmaf(C1, v.z, C0) : v.z;
            tr.w = pp ? fmaf(C1, v.w, C0) : v.w;
            ushort4 o;
            o.x = f2bf(d2 * tr.x); o.y = f2bf(d2 * tr.y);
            o.z = f2bf(d2 * tr.z); o.w = f2bf(d2 * tr.w);
            ((ushort4*)xt)[(size_t)n2 * 16 + (i & 15)] = o;
        }
    }
}

// ---- partition (cols only): digit bases from bsum, then scatter (col<<16)|row.
__global__ __launch_bounds__(1024) void k_part(const int* __restrict__ row,
                                               const int* __restrict__ col, int E, int chunk,
                                               const int* __restrict__ excl,
                                               const int* __restrict__ bsum,
                                               unsigned* __restrict__ cbuf) {
    __shared__ int sc[256];
    __shared__ int offc[256];
    int t = threadIdx.x, b = blockIdx.x;
    if (t < 256) sc[t] = bsum[t];
    __syncthreads();
    for (int off = 1; off < 256; off <<= 1) {
        int u = (t < 256 && t >= off) ? sc[t - off] : 0;
        __syncthreads();
        if (t < 256) sc[t] += u;
        __syncthreads();
    }
    if (t < 256) offc[t] = sc[t] - bsum[t] + excl[t * 256 + b];
    __syncthreads();
    int lo = b * chunk, hi = min(E, lo + chunk);
    int base = lo + t * 4;
    for (; base + 3 < hi; base += 4096) {
        int4 r4 = *(const int4*)&row[base];
        int4 c4 = *(const int4*)&col[base];
        int p0 = atomicAdd(&offc[c4.x >> 8], 1);
        cbuf[p0] = ((unsigned)c4.x << 16) | (unsigned)r4.x;
        int p1 = atomicAdd(&offc[c4.y >> 8], 1);
        cbuf[p1] = ((unsigned)c4.y << 16) | (unsigned)r4.y;
        int p2 = atomicAdd(&offc[c4.z >> 8], 1);
        cbuf[p2] = ((unsigned)c4.z << 16) | (unsigned)r4.z;
        int p3 = atomicAdd(&offc[c4.w >> 8], 1);
        cbuf[p3] = ((unsigned)c4.w << 16) | (unsigned)r4.w;
    }
    for (; base < hi; ++base) {
        int r = row[base], c = col[base];
        int pc = atomicAdd(&offc[c >> 8], 1);
        cbuf[pc] = ((unsigned)c << 16) | (unsigned)r;
    }
}

// ---- per-bucket CSR build: cntC/colStart + eSrc[pos] = row (u16) ----
__global__ __launch_bounds__(256) void k_csr(const unsigned* __restrict__ cbuf,
                                             const int* __restrict__ bsum, int N,
                                             int* __restrict__ cntC, int* __restrict__ colStart,
                                             unsigned short* __restrict__ eSrc) {
    __shared__ int s1[256], s2[256], s3[256];
    int t = threadIdx.x, b = blockIdx.x;
    s1[t] = (t < b) ? bsum[t] : 0;          // prefix of col-digit totals
    __syncthreads();
    for (int off = 128; off > 0; off >>= 1) {
        if (t < off) s1[t] += s1[t + off];
        __syncthreads();
    }
    int cs = s1[0];
    int ce = cs + bsum[b];
    __syncthreads();
    s1[t] = 0; s3[t] = 0;
    __syncthreads();
    for (int i = cs + t; i < ce; i += 256) atomicAdd(&s1[(cbuf[i] >> 16) & 255], 1);
    __syncthreads();
    int v = s1[t];
    s2[t] = v;
    __syncthreads();
    for (int off = 1; off < 256; off <<= 1) {
        int u = (t >= off) ? s2[t - off] : 0;
        __syncthreads();
        s2[t] += u;
        __syncthreads();
    }
    int excl = s2[t] - v;
    int c = b * 256 + t;
    if (c < N) { cntC[c] = v; colStart[c] = cs + excl; }
    __syncthreads();
    s2[t] = excl;
    __syncthreads();
    for (int i = cs + t; i < ce; i += 256) {
        unsigned e = cbuf[i];
        int d = (e >> 16) & 255;
        int pos = cs + s2[d] + atomicAdd(&s3[d], 1);
        eSrc[pos] = (unsigned short)(e & 0xFFFFu);
    }
}

// conv1 by gather: agg1b[c] = bf16( dis_c * (xt_c + sum_r xt_r) )
// u32 lanes: 32 lanes per column (2 bf16 dims each), 2 columns per wave, 8x unroll.
__global__ __launch_bounds__(256) void k_gather1(const unsigned short* __restrict__ xt,
                                                 const unsigned short* __restrict__ eSrc,
                                                 const int* __restrict__ colStart,
                                                 const int* __restrict__ cntC,
                                                 const float* __restrict__ dis,
                                                 unsigned short* __restrict__ agg1b, int N) {
    int t = blockIdx.x * blockDim.x + threadIdx.x;
    int c = t >> 5, j = t & 31;
    if (c >= N) return;
    const unsigned* x32 = (const unsigned*)xt;
    unsigned u = x32[(size_t)c * 32 + j];      // self loop term (dims 2j, 2j+1)
    float s0 = bfl(u), s1 = bfh(u);
    int start = colStart[c], cnt = cntC[c];
    for (int base = 0; base < cnt; base += 32) {
        int m = min(cnt - base, 32);
        int ids = (j < m) ? (int)eSrc[start + base + j] : 0;
        int k = 0;
        for (; k + 8 <= m; k += 8) {
            int r0 = __shfl(ids, k, 32),     r1 = __shfl(ids, k + 1, 32);
            int r2 = __shfl(ids, k + 2, 32), r3 = __shfl(ids, k + 3, 32);
            int r4 = __shfl(ids, k + 4, 32), r5 = __shfl(ids, k + 5, 32);
            int r6 = __shfl(ids, k + 6, 32), r7 = __shfl(ids, k + 7, 32);
            unsigned u0 = x32[(size_t)r0 * 32 + j];
            unsigned u1 = x32[(size_t)r1 * 32 + j];
            unsigned u2 = x32[(size_t)r2 * 32 + j];
            unsigned u3 = x32[(size_t)r3 * 32 + j];
            unsigned u4 = x32[(size_t)r4 * 32 + j];
            unsigned u5 = x32[(size_t)r5 * 32 + j];
            unsigned u6 = x32[(size_t)r6 * 32 + j];
            unsigned u7 = x32[(size_t)r7 * 32 + j];
            s0 += bfl(u0); s1 += bfh(u0);
            s0 += bfl(u1); s1 += bfh(u1);
            s0 += bfl(u2); s1 += bfh(u2);
            s0 += bfl(u3); s1 += bfh(u3);
            s0 += bfl(u4); s1 += bfh(u4);
            s0 += bfl(u5); s1 += bfh(u5);
            s0 += bfl(u6); s1 += bfh(u6);
            s0 += bfl(u7); s1 += bfh(u7);
        }
        for (; k + 4 <= m; k += 4) {
            int r0 = __shfl(ids, k, 32),     r1 = __shfl(ids, k + 1, 32);
            int r2 = __shfl(ids, k + 2, 32), r3 = __shfl(ids, k + 3, 32);
            unsigned u0 = x32[(size_t)r0 * 32 + j];
            unsigned u1 = x32[(size_t)r1 * 32 + j];
            unsigned u2 = x32[(size_t)r2 * 32 + j];
            unsigned u3 = x32[(size_t)r3 * 32 + j];
            s0 += bfl(u0); s1 += bfh(u0);
            s0 += bfl(u1); s1 += bfh(u1);
            s0 += bfl(u2); s1 += bfh(u2);
            s0 += bfl(u3); s1 += bfh(u3);
        }
        for (; k < m; ++k) {
            int r = __shfl(ids, k, 32);
            unsigned uu = x32[(size_t)r * 32 + j];
            s0 += bfl(uu); s1 += bfh(uu);
        }
    }
    float dv = dis[c];
    unsigned o = ((unsigned)f2bf(dv * s1) << 16) | (unsigned)f2bf(dv * s0);
    ((unsigned*)agg1b)[(size_t)c * 32 + j] = o;
}

// ---- MFMA MLP: hps = bf16(dis * (relu(A@W1+b1)@W2)); 64-node tile, 4 waves ----
__global__ __launch_bounds__(256) void k_mlp_mfma(const unsigned short* __restrict__ agg1b,
                                                  const unsigned short* __restrict__ W1b,
                                                  const float* __restrict__ b1,
                                                  const unsigned short* __restrict__ W2b,
                                                  const float* __restrict__ dis,
                                                  unsigned short* __restrict__ hps, int N) {
    __shared__ unsigned short hidA[4][16 * 136];   // per-wave 16 x 128 (+8 pad)
    const int t = threadIdx.x;
    const int w = t >> 6, l = t & 63;
    const int q = l >> 4, lm = l & 15;
    const int rowbase = blockIdx.x * 64 + w * 16;

    bf16x8 a0, a1;
    {
        int node = rowbase + lm;
        if (node >= N) node = N - 1;
        const bf16x8* pa = (const bf16x8*)(agg1b + (size_t)node * 64);
        a0 = pa[q];
        a1 = pa[4 + q];
    }
    float dvals[4];
    #pragma unroll
    for (int r = 0; r < 4; ++r) {
        int node = rowbase + q * 4 + r;
        dvals[r] = (node < N) ? dis[node] : 0.f;
    }

    const bf16x8* w1f = (const bf16x8*)W1b;
    #pragma unroll
    for (int nt = 0; nt < 8; ++nt) {
        float bv = b1[nt * 16 + lm];
        f32x4 acc = {bv, bv, bv, bv};
        acc = __builtin_amdgcn_mfma_f32_16x16x32_bf16(a0, w1f[(nt * 2 + 0) * 64 + l], acc, 0, 0, 0);
        acc = __builtin_amdgcn_mfma_f32_16x16x32_bf16(a1, w1f[(nt * 2 + 1) * 64 + l], acc, 0, 0, 0);
        #pragma unroll
        for (int r = 0; r < 4; ++r)
            hidA[w][(q * 4 + r) * 136 + nt * 16 + lm] = f2bf(fmaxf(acc[r], 0.f));
    }
    __syncthreads();

    bf16x8 ha[4];
    #pragma unroll
    for (int kt = 0; kt < 4; ++kt)
        ha[kt] = *(const bf16x8*)&hidA[w][lm * 136 + kt * 32 + q * 8];

    const bf16x8* w2f = (const bf16x8*)W2b;
    #pragma unroll
    for (int nt = 0; nt < 2; ++nt) {
        f32x4 acc = {0.f, 0.f, 0.f, 0.f};
        #pragma unroll
        for (int kt = 0; kt < 4; ++kt)
            acc = __builtin_amdgcn_mfma_f32_16x16x32_bf16(ha[kt], w2f[(nt * 4 + kt) * 64 + l], acc, 0, 0, 0);
        #pragma unroll
        for (int r = 0; r < 4; ++r) {
            int node = rowbase + q * 4 + r;
            if (node < N)
                hps[(size_t)node * 32 + nt * 16 + lm] = f2bf(acc[r] * dvals[r]);
        }
    }
}

// conv2 by gather: out[c] = b2 - dis_c * (hps_c + sum_r hps_r)
// u32 lanes: 16 lanes per column (2 bf16 dims each), 4 columns per wave, 8x unroll.
__global__ __launch_bounds__(256) void k_gather2(const unsigned short* __restrict__ hps,
                                                 const unsigned short* __restrict__ eSrc,
                                                 const int* __restrict__ colStart,
                                                 const int* __restrict__ cntC,
                                                 const float* __restrict__ dis,
                                                 const float* __restrict__ b2,
                                                 float* __restrict__ out, int N) {
    int t = blockIdx.x * blockDim.x + threadIdx.x;
    int c = t >> 4, j = t & 15;
    if (c >= N) return;
    const unsigned* h32 = (const unsigned*)hps;
    unsigned u = h32[(size_t)c * 16 + j];      // self loop (dims 2j, 2j+1)
    float s0 = bfl(u), s1 = bfh(u);
    int start = colStart[c], cnt = cntC[c];
    for (int base = 0; base < cnt; base += 16) {
        int m = min(cnt - base, 16);
        int ids = (j < m) ? (int)eSrc[start + base + j] : 0;
        int k = 0;
        for (; k + 8 <= m; k += 8) {
            int r0 = __shfl(ids, k, 16),     r1 = __shfl(ids, k + 1, 16);
            int r2 = __shfl(ids, k + 2, 16), r3 = __shfl(ids, k + 3, 16);
            int r4 = __shfl(ids, k + 4, 16), r5 = __shfl(ids, k + 5, 16);
            int r6 = __shfl(ids, k + 6, 16), r7 = __shfl(ids, k + 7, 16);
            unsigned u0 = h32[(size_t)r0 * 16 + j];
            unsigned u1 = h32[(size_t)r1 * 16 + j];
            unsigned u2 = h32[(size_t)r2 * 16 + j];
            unsigned u3 = h32[(size_t)r3 * 16 + j];
            unsigned u4 = h32[(size_t)r4 * 16 + j];
            unsigned u5 = h32[(size_t)r5 * 16 + j];
            unsigned u6 = h32[(size_t)r6 * 16 + j];
            unsigned u7 = h32[(size_t)r7 * 16 + j];
            s0 += bfl(u0); s1 += bfh(u0);
            s0 += bfl(u1); s1 += bfh(u1);
            s0 += bfl(u2); s1 += bfh(u2);
            s0 += bfl(u3); s1 += bfh(u3);
            s0 += bfl(u4); s1 += bfh(u4);
            s0 += bfl(u5); s1 += bfh(u5);
            s0 += bfl(u6); s1 += bfh(u6);
            s0 += bfl(u7); s1 += bfh(u7);
        }
        for (; k + 4 <= m; k += 4) {
            int r0 = __shfl(ids, k, 16),     r1 = __shfl(ids, k + 1, 16);
            int r2 = __shfl(ids, k + 2, 16), r3 = __shfl(ids, k + 3, 16);
            unsigned u0 = h32[(size_t)r0 * 16 + j];
            unsigned u1 = h32[(size_t)r1 * 16 + j];
            unsigned u2 = h32[(size_t)r2 * 16 + j];
            unsigned u3 = h32[(size_t)r3 * 16 + j];
            s0 += bfl(u0); s1 += bfh(u0);
            s0 += bfl(u1); s1 += bfh(u1);
            s0 += bfl(u2); s1 += bfh(u2);
            s0 += bfl(u3); s1 += bfh(u3);
        }
        for (; k < m; ++k) {
            int r = __shfl(ids, k, 16);
            unsigned uu = h32[(size_t)r * 16 + j];
            s0 += bfl(uu); s1 += bfh(uu);
        }
    }
    float dv = dis[c];
    float2 bb = ((const float2*)b2)[j];
    float2 o;
    o.x = bb.x - dv * s0;
    o.y = bb.y - dv * s1;
    ((float2*)out)[(size_t)c * 16 + j] = o;
}

extern "C" void kernel_launch(void* const* d_in, const int* in_sizes, int n_in,
                              void* d_out, int out_size, void* d_ws, size_t ws_size,
                              hipStream_t stream) {
    const float* x    = (const float*)d_in[0];
    const int*   ei   = (const int*)d_in[1];
    const int*   priv = (const int*)d_in[2];
    const float* W1   = (const float*)d_in[3];
    const float* b1   = (const float*)d_in[4];
    const float* W2   = (const float*)d_in[5];
    const float* b2   = (const float*)d_in[6];
    float* out = (float*)d_out;

    const int N = in_sizes[2];
    const int E = in_sizes[1] / 2;
    const int* row = ei;
    const int* col = ei + E;

    char* ws = (char*)d_ws;
    size_t off = 0;
    auto take = [&](size_t bytes) { char* p = ws + off; off = (off + bytes + 255) & ~(size_t)255; return p; };
    int*            hist     = (int*)           take((size_t)65536 * 4);
    int*            excl     = (int*)           take((size_t)65536 * 4);
    int*            bsum     = (int*)           take(256 * 4);
    int*            deg      = (int*)           take((size_t)N * 4);
    unsigned short* W1b      = (unsigned short*)take((size_t)8192 * 2);
    unsigned short* W2b      = (unsigned short*)take((size_t)4096 * 2);
    unsigned*       cbuf     = (unsigned*)      take((size_t)E * 4);
    float*          dis      = (float*)         take((size_t)N * 4);
    int*            cntC     = (int*)           take((size_t)N * 4);
    int*            colStart = (int*)           take((size_t)N * 4);
    unsigned short* eSrc     = (unsigned short*)take((size_t)E * 2);
    unsigned short* xt       = (unsigned short*)take((size_t)N * 64 * 2);
    unsigned short* agg1b    = (unsigned short*)take((size_t)N * 64 * 2);
    unsigned short* hps      = (unsigned short*)take((size_t)N * 32 * 2);
    (void)ws_size;

    const int chunk = (((E + 255) / 256) + 3) & ~3;   // multiple of 4 -> int4-aligned
    const int nbk = (N + 255) / 256;                  // node buckets (196 < 255)

    hipMemsetAsync(deg, 0, (size_t)N * 4, stream);
    k_hist2   <<<256, 1024, 0, stream>>>(row, col, E, chunk, hist, deg, W1, W2, W1b, W2b);
    k_scan2   <<<256 + nbk, 256, 0, stream>>>(hist, excl, bsum, 65536, deg, priv, x, N, dis, xt);
    k_part    <<<256, 1024, 0, stream>>>(row, col, E, chunk, excl, bsum, cbuf);
    k_csr     <<<nbk, 256, 0, stream>>>(cbuf, bsum, N, cntC, colStart, eSrc);
    k_gather1 <<<((size_t)N * 32 + 255) / 256, 256, 0, stream>>>(xt, eSrc, colStart, cntC, dis, agg1b, N);
    k_mlp_mfma<<<(N + 63) / 64, 256, 0, stream>>>(agg1b, W1b, b1, W2b, dis, hps, N);
    k_gather2 <<<((size_t)N * 16 + 255) / 256, 256, 0, stream>>>(hps, eSrc, colStart, cntC, dis, b2, out, N);
}

// Round 8
// 146.458 us; speedup vs baseline: 1.2189x; 1.2189x over previous
//
#include <hip/hip_runtime.h>
#include <math.h>

// DP-GCN constants (EPS=1, ALPHA=0.5, DELTA=1):
//   transformed = ((e+1)*x - 1) * (1/(e-1)) + 0.5 = C1*x + C0
#define C1 2.163953413738653f
#define C0 -0.081976706869326f

// NOTE: assumes N <= 65536 so node ids fit u16 (N=50000 here).

typedef __attribute__((ext_vector_type(8))) short bf16x8;
typedef __attribute__((ext_vector_type(4))) float f32x4;

static __device__ __forceinline__ unsigned short f2bf(float f) {   // RTN-even
    unsigned b = __float_as_uint(f);
    return (unsigned short)((b + 0x7FFFu + ((b >> 16) & 1u)) >> 16);
}
static __device__ __forceinline__ float bf2f(unsigned short u) {
    return __uint_as_float((unsigned)u << 16);
}
// unpack a u32 holding two bf16 (little-endian: low half = even dim)
static __device__ __forceinline__ float bfl(unsigned u) { return __uint_as_float(u << 16); }
static __device__ __forceinline__ float bfh(unsigned u) { return __uint_as_float(u & 0xFFFF0000u); }

// ---- dual per-block histogram of col>>8 / row>>8; blocks 0/1 also convert W1/W2
// to bf16 swizzled into MFMA B-fragment order. hist[d*256+b] cols, [65536+d*256+b] rows.
// chunk is a multiple of 4 so &row[lo] is 16B-aligned for int4 loads.
__global__ __launch_bounds__(1024) void k_hist2(const int* __restrict__ row,
                                                const int* __restrict__ col, int E, int chunk,
                                                int* __restrict__ hist,
                                                const float* __restrict__ W1,
                                                const float* __restrict__ W2,
                                                unsigned short* __restrict__ W1b,
                                                unsigned short* __restrict__ W2b) {
    __shared__ int hc[256], hr[256];
    int t = threadIdx.x, b = blockIdx.x;
    if (t < 256) { hc[t] = 0; hr[t] = 0; }
    __syncthreads();
    int lo = b * chunk, hi = min(E, lo + chunk);
    int base = lo + t * 4;
    for (; base + 3 < hi; base += 4096) {
        int4 r4 = *(const int4*)&row[base];
        int4 c4 = *(const int4*)&col[base];
        atomicAdd(&hc[c4.x >> 8], 1); atomicAdd(&hc[c4.y >> 8], 1);
        atomicAdd(&hc[c4.z >> 8], 1); atomicAdd(&hc[c4.w >> 8], 1);
        atomicAdd(&hr[r4.x >> 8], 1); atomicAdd(&hr[r4.y >> 8], 1);
        atomicAdd(&hr[r4.z >> 8], 1); atomicAdd(&hr[r4.w >> 8], 1);
    }
    for (; base < hi; ++base) {
        atomicAdd(&hc[col[base] >> 8], 1);
        atomicAdd(&hr[row[base] >> 8], 1);
    }
    __syncthreads();
    if (t < 256) {
        hist[t * 256 + b] = hc[t];
        hist[65536 + t * 256 + b] = hr[t];
    }
    // B-fragment swizzle: frag element j of lane l for (ntile, ktile) holds
    // B[k = kt*32 + (l>>4)*8 + j][n = nt*16 + (l&15)], stored contiguously.
    if (b == 0) {
        for (int i = t; i < 8192; i += 1024) {           // W1: 8 nt x 2 kt
            int j = i & 7, l2 = (i >> 3) & 63, kt = (i >> 9) & 1, nt = i >> 10;
            int k = kt * 32 + (l2 >> 4) * 8 + j, n = nt * 16 + (l2 & 15);
            W1b[i] = f2bf(W1[k * 128 + n]);
        }
    } else if (b == 1) {
        for (int i = t; i < 4096; i += 1024) {           // W2: 2 nt x 4 kt
            int j = i & 7, l2 = (i >> 3) & 63, kt = (i >> 9) & 3, nt = i >> 11;
            int k = kt * 32 + (l2 >> 4) * 8 + j, n = nt * 16 + (l2 & 15);
            W2b[i] = f2bf(W2[k * 32 + n]);
        }
    }
}

// ---- level-1 exclusive scan: scan-block d = digit d's 256 per-block counts.
// excl[d*256+b] = within-digit prefix over blocks<b; bsum[d] = digit total.
__global__ void k_scan_a(const int* __restrict__ cnt, int* __restrict__ excl,
                         int* __restrict__ bsum, int n) {
    __shared__ int s[256];
    int idx = blockIdx.x * 256 + threadIdx.x;
    int v = (idx < n) ? cnt[idx] : 0;
    s[threadIdx.x] = v;
    __syncthreads();
    for (int off = 1; off < 256; off <<= 1) {
        int t = (threadIdx.x >= off) ? s[threadIdx.x - off] : 0;
        __syncthreads();
        s[threadIdx.x] += t;
        __syncthreads();
    }
    if (idx < n) excl[idx] = s[threadIdx.x] - v;
    if (threadIdx.x == 255) bsum[blockIdx.x] = s[255];
}

// ---- partition: digit bases from bsum (two concurrent 256-scans), then scatter.
__global__ __launch_bounds__(1024) void k_part(const int* __restrict__ row,
                                               const int* __restrict__ col, int E, int chunk,
                                               const int* __restrict__ excl,
                                               const int* __restrict__ bsum,
                                               unsigned* __restrict__ cbuf,
                                               unsigned short* __restrict__ rbuf) {
    __shared__ int sc[512];
    __shared__ int offc[256], offr[256];
    int t = threadIdx.x, b = blockIdx.x;
    // concurrent exclusive scans: lanes 0-255 col digits, 256-511 row digits
    if (t < 512) sc[t] = bsum[t];
    __syncthreads();
    int half = t >> 8, d = t & 255;
    for (int off = 1; off < 256; off <<= 1) {
        int u = (t < 512 && d >= off) ? sc[half * 256 + d - off] : 0;
        __syncthreads();
        if (t < 512) sc[t] += u;
        __syncthreads();
    }
    if (t < 256) offc[t] = sc[t] - bsum[t] + excl[t * 256 + b];
    else if (t < 512) offr[d] = sc[t] - bsum[t] + excl[65536 + d * 256 + b];
    __syncthreads();
    int lo = b * chunk, hi = min(E, lo + chunk);
    int base = lo + t * 4;
    for (; base + 3 < hi; base += 4096) {
        int4 r4 = *(const int4*)&row[base];
        int4 c4 = *(const int4*)&col[base];
        int p0 = atomicAdd(&offc[c4.x >> 8], 1);
        cbuf[p0] = ((unsigned)c4.x << 16) | (unsigned)r4.x;
        int p1 = atomicAdd(&offc[c4.y >> 8], 1);
        cbuf[p1] = ((unsigned)c4.y << 16) | (unsigned)r4.y;
        int p2 = atomicAdd(&offc[c4.z >> 8], 1);
        cbuf[p2] = ((unsigned)c4.z << 16) | (unsigned)r4.z;
        int p3 = atomicAdd(&offc[c4.w >> 8], 1);
        cbuf[p3] = ((unsigned)c4.w << 16) | (unsigned)r4.w;
        int q0 = atomicAdd(&offr[r4.x >> 8], 1); rbuf[q0] = (unsigned short)r4.x;
        int q1 = atomicAdd(&offr[r4.y >> 8], 1); rbuf[q1] = (unsigned short)r4.y;
        int q2 = atomicAdd(&offr[r4.z >> 8], 1); rbuf[q2] = (unsigned short)r4.z;
        int q3 = atomicAdd(&offr[r4.w >> 8], 1); rbuf[q3] = (unsigned short)r4.w;
    }
    for (; base < hi; ++base) {
        int r = row[base], c = col[base];
        int pc = atomicAdd(&offc[c >> 8], 1);
        cbuf[pc] = ((unsigned)c << 16) | (unsigned)r;
        int pr = atomicAdd(&offr[r >> 8], 1);
        rbuf[pr] = (unsigned short)r;
    }
}

// ---- merged per-bucket build: blocks [0,nbk) deg->dis->xt; [nbk,2nbk) CSR ----
__global__ __launch_bounds__(256) void k_build(const unsigned short* __restrict__ rbuf,
                                               const unsigned* __restrict__ cbuf,
                                               const int* __restrict__ bsum,
                                               const int* __restrict__ priv,
                                               const float* __restrict__ x, int N, int E, int nbk,
                                               float* __restrict__ dis,
                                               unsigned short* __restrict__ xt,
                                               int* __restrict__ cntC, int* __restrict__ colStart,
                                               unsigned short* __restrict__ eSrc) {
    __shared__ int s1[256], s2[256], s3[256];
    int t = threadIdx.x;
    if ((int)blockIdx.x < nbk) {
        // ---- deg -> dis -> bf16 xt ----
        int b = blockIdx.x;
        s1[t] = (t < b) ? bsum[256 + t] : 0;   // prefix of row-digit totals
        __syncthreads();
        for (int off = 128; off > 0; off >>= 1) {
            if (t < off) s1[t] += s1[t + off];
            __syncthreads();
        }
        int rs = s1[0];
        int re = rs + bsum[256 + b];
        __syncthreads();
        s1[t] = 0;
        __syncthreads();
        for (int i = rs + t; i < re; i += 256) atomicAdd(&s1[rbuf[i] & 255], 1);
        __syncthreads();
        int node = b * 256 + t;
        float dv = rsqrtf((float)(s1[t] + 1));       // +1 self loop
        if (node < N) {
            dis[node] = dv;
            s2[t] = __float_as_int(dv);
            s3[t] = priv[node];
        } else { s2[t] = 0; s3[t] = 0; }
        __syncthreads();
        int base = b * 256;
        for (int i = t; i < 256 * 16; i += 256) {     // 16 float4 per node
            int ln = i >> 4;
            int n2 = base + ln;
            if (n2 >= N) continue;
            float d2 = __int_as_float(s2[ln]);
            int p = s3[ln];
            float4 v = ((const float4*)x)[(size_t)n2 * 16 + (i & 15)];
            float4 tr;
            tr.x = p ? fmaf(C1, v.x, C0) : v.x;
            tr.y = p ? fmaf(C1, v.y, C0) : v.y;
            tr.z = p ? fmaf(C1, v.z, C0) : v.z;
            tr.w = p ? fmaf(C1, v.w, C0) : v.w;
            ushort4 o;
            o.x = f2bf(d2 * tr.x); o.y = f2bf(d2 * tr.y);
            o.z = f2bf(d2 * tr.z); o.w = f2bf(d2 * tr.w);
            ((ushort4*)xt)[(size_t)n2 * 16 + (i & 15)] = o;
        }
    } else {
        // ---- CSR: cntC/colStart + eSrc[pos] = row (u16) ----
        int b = blockIdx.x - nbk;
        s1[t] = (t < b) ? bsum[t] : 0;          // prefix of col-digit totals
        __syncthreads();
        for (int off = 128; off > 0; off >>= 1) {
            if (t < off) s1[t] += s1[t + off];
            __syncthreads();
        }
        int cs = s1[0];
        int ce = cs + bsum[b];
        __syncthreads();
        s1[t] = 0; s3[t] = 0;
        __syncthreads();
        for (int i = cs + t; i < ce; i += 256) atomicAdd(&s1[(cbuf[i] >> 16) & 255], 1);
        __syncthreads();
        int v = s1[t];
        s2[t] = v;
        __syncthreads();
        for (int off = 1; off < 256; off <<= 1) {
            int u = (t >= off) ? s2[t - off] : 0;
            __syncthreads();
            s2[t] += u;
            __syncthreads();
        }
        int excl = s2[t] - v;
        int c = b * 256 + t;
        if (c < N) { cntC[c] = v; colStart[c] = cs + excl; }
        __syncthreads();
        s2[t] = excl;
        __syncthreads();
        for (int i = cs + t; i < ce; i += 256) {
            unsigned e = cbuf[i];
            int d = (e >> 16) & 255;
            int pos = cs + s2[d] + atomicAdd(&s3[d], 1);
            eSrc[pos] = (unsigned short)(e & 0xFFFFu);
        }
    }
}

// conv1 by gather: agg1b[c] = bf16( dis_c * (xt_c + sum_r xt_r) )
// u32 lanes: 32 lanes per column (2 bf16 dims each), 2 columns per wave, 8x unroll.
__global__ __launch_bounds__(256) void k_gather1(const unsigned short* __restrict__ xt,
                                                 const unsigned short* __restrict__ eSrc,
                                                 const int* __restrict__ colStart,
                                                 const int* __restrict__ cntC,
                                                 const float* __restrict__ dis,
                                                 unsigned short* __restrict__ agg1b, int N) {
    int t = blockIdx.x * blockDim.x + threadIdx.x;
    int c = t >> 5, j = t & 31;
    if (c >= N) return;
    const unsigned* x32 = (const unsigned*)xt;
    unsigned u = x32[(size_t)c * 32 + j];      // self loop term (dims 2j, 2j+1)
    float s0 = bfl(u), s1 = bfh(u);
    int start = colStart[c], cnt = cntC[c];
    for (int base = 0; base < cnt; base += 32) {
        int m = min(cnt - base, 32);
        int ids = (j < m) ? (int)eSrc[start + base + j] : 0;
        int k = 0;
        for (; k + 8 <= m; k += 8) {
            int r0 = __shfl(ids, k, 32),     r1 = __shfl(ids, k + 1, 32);
            int r2 = __shfl(ids, k + 2, 32), r3 = __shfl(ids, k + 3, 32);
            int r4 = __shfl(ids, k + 4, 32), r5 = __shfl(ids, k + 5, 32);
            int r6 = __shfl(ids, k + 6, 32), r7 = __shfl(ids, k + 7, 32);
            unsigned u0 = x32[(size_t)r0 * 32 + j];
            unsigned u1 = x32[(size_t)r1 * 32 + j];
            unsigned u2 = x32[(size_t)r2 * 32 + j];
            unsigned u3 = x32[(size_t)r3 * 32 + j];
            unsigned u4 = x32[(size_t)r4 * 32 + j];
            unsigned u5 = x32[(size_t)r5 * 32 + j];
            unsigned u6 = x32[(size_t)r6 * 32 + j];
            unsigned u7 = x32[(size_t)r7 * 32 + j];
            s0 += bfl(u0); s1 += bfh(u0);
            s0 += bfl(u1); s1 += bfh(u1);
            s0 += bfl(u2); s1 += bfh(u2);
            s0 += bfl(u3); s1 += bfh(u3);
            s0 += bfl(u4); s1 += bfh(u4);
            s0 += bfl(u5); s1 += bfh(u5);
            s0 += bfl(u6); s1 += bfh(u6);
            s0 += bfl(u7); s1 += bfh(u7);
        }
        for (; k + 4 <= m; k += 4) {
            int r0 = __shfl(ids, k, 32),     r1 = __shfl(ids, k + 1, 32);
            int r2 = __shfl(ids, k + 2, 32), r3 = __shfl(ids, k + 3, 32);
            unsigned u0 = x32[(size_t)r0 * 32 + j];
            unsigned u1 = x32[(size_t)r1 * 32 + j];
            unsigned u2 = x32[(size_t)r2 * 32 + j];
            unsigned u3 = x32[(size_t)r3 * 32 + j];
            s0 += bfl(u0); s1 += bfh(u0);
            s0 += bfl(u1); s1 += bfh(u1);
            s0 += bfl(u2); s1 += bfh(u2);
            s0 += bfl(u3); s1 += bfh(u3);
        }
        for (; k < m; ++k) {
            int r = __shfl(ids, k, 32);
            unsigned uu = x32[(size_t)r * 32 + j];
            s0 += bfl(uu); s1 += bfh(uu);
        }
    }
    float dv = dis[c];
    unsigned o = ((unsigned)f2bf(dv * s1) << 16) | (unsigned)f2bf(dv * s0);
    ((unsigned*)agg1b)[(size_t)c * 32 + j] = o;
}

// ---- MFMA MLP: hps = bf16(dis * (relu(A@W1+b1)@W2)); 64-node tile, 4 waves ----
__global__ __launch_bounds__(256) void k_mlp_mfma(const unsigned short* __restrict__ agg1b,
                                                  const unsigned short* __restrict__ W1b,
                                                  const float* __restrict__ b1,
                                                  const unsigned short* __restrict__ W2b,
                                                  const float* __restrict__ dis,
                                                  unsigned short* __restrict__ hps, int N) {
    __shared__ unsigned short hidA[4][16 * 136];   // per-wave 16 x 128 (+8 pad)
    const int t = threadIdx.x;
    const int w = t >> 6, l = t & 63;
    const int q = l >> 4, lm = l & 15;
    const int rowbase = blockIdx.x * 64 + w * 16;

    bf16x8 a0, a1;
    {
        int node = rowbase + lm;
        if (node >= N) node = N - 1;
        const bf16x8* pa = (const bf16x8*)(agg1b + (size_t)node * 64);
        a0 = pa[q];
        a1 = pa[4 + q];
    }
    float dvals[4];
    #pragma unroll
    for (int r = 0; r < 4; ++r) {
        int node = rowbase + q * 4 + r;
        dvals[r] = (node < N) ? dis[node] : 0.f;
    }

    const bf16x8* w1f = (const bf16x8*)W1b;
    #pragma unroll
    for (int nt = 0; nt < 8; ++nt) {
        float bv = b1[nt * 16 + lm];
        f32x4 acc = {bv, bv, bv, bv};
        acc = __builtin_amdgcn_mfma_f32_16x16x32_bf16(a0, w1f[(nt * 2 + 0) * 64 + l], acc, 0, 0, 0);
        acc = __builtin_amdgcn_mfma_f32_16x16x32_bf16(a1, w1f[(nt * 2 + 1) * 64 + l], acc, 0, 0, 0);
        #pragma unroll
        for (int r = 0; r < 4; ++r)
            hidA[w][(q * 4 + r) * 136 + nt * 16 + lm] = f2bf(fmaxf(acc[r], 0.f));
    }
    __syncthreads();

    bf16x8 ha[4];
    #pragma unroll
    for (int kt = 0; kt < 4; ++kt)
        ha[kt] = *(const bf16x8*)&hidA[w][lm * 136 + kt * 32 + q * 8];

    const bf16x8* w2f = (const bf16x8*)W2b;
    #pragma unroll
    for (int nt = 0; nt < 2; ++nt) {
        f32x4 acc = {0.f, 0.f, 0.f, 0.f};
        #pragma unroll
        for (int kt = 0; kt < 4; ++kt)
            acc = __builtin_amdgcn_mfma_f32_16x16x32_bf16(ha[kt], w2f[(nt * 4 + kt) * 64 + l], acc, 0, 0, 0);
        #pragma unroll
        for (int r = 0; r < 4; ++r) {
            int node = rowbase + q * 4 + r;
            if (node < N)
                hps[(size_t)node * 32 + nt * 16 + lm] = f2bf(acc[r] * dvals[r]);
        }
    }
}

// conv2 by gather: out[c] = b2 - dis_c * (hps_c + sum_r hps_r)
// u32 lanes: 16 lanes per column (2 bf16 dims each), 4 columns per wave, 8x unroll.
__global__ __launch_bounds__(256) void k_gather2(const unsigned short* __restrict__ hps,
                                                 const unsigned short* __restrict__ eSrc,
                                                 const int* __restrict__ colStart,
                                                 const int* __restrict__ cntC,
                                                 const float* __restrict__ dis,
                                                 const float* __restrict__ b2,
                                                 float* __restrict__ out, int N) {
    int t = blockIdx.x * blockDim.x + threadIdx.x;
    int c = t >> 4, j = t & 15;
    if (c >= N) return;
    const unsigned* h32 = (const unsigned*)hps;
    unsigned u = h32[(size_t)c * 16 + j];      // self loop (dims 2j, 2j+1)
    float s0 = bfl(u), s1 = bfh(u);
    int start = colStart[c], cnt = cntC[c];
    for (int base = 0; base < cnt; base += 16) {
        int m = min(cnt - base, 16);
        int ids = (j < m) ? (int)eSrc[start + base + j] : 0;
        int k = 0;
        for (; k + 8 <= m; k += 8) {
            int r0 = __shfl(ids, k, 16),     r1 = __shfl(ids, k + 1, 16);
            int r2 = __shfl(ids, k + 2, 16), r3 = __shfl(ids, k + 3, 16);
            int r4 = __shfl(ids, k + 4, 16), r5 = __shfl(ids, k + 5, 16);
            int r6 = __shfl(ids, k + 6, 16), r7 = __shfl(ids, k + 7, 16);
            unsigned u0 = h32[(size_t)r0 * 16 + j];
            unsigned u1 = h32[(size_t)r1 * 16 + j];
            unsigned u2 = h32[(size_t)r2 * 16 + j];
            unsigned u3 = h32[(size_t)r3 * 16 + j];
            unsigned u4 = h32[(size_t)r4 * 16 + j];
            unsigned u5 = h32[(size_t)r5 * 16 + j];
            unsigned u6 = h32[(size_t)r6 * 16 + j];
            unsigned u7 = h32[(size_t)r7 * 16 + j];
            s0 += bfl(u0); s1 += bfh(u0);
            s0 += bfl(u1); s1 += bfh(u1);
            s0 += bfl(u2); s1 += bfh(u2);
            s0 += bfl(u3); s1 += bfh(u3);
            s0 += bfl(u4); s1 += bfh(u4);
            s0 += bfl(u5); s1 += bfh(u5);
            s0 += bfl(u6); s1 += bfh(u6);
            s0 += bfl(u7); s1 += bfh(u7);
        }
        for (; k + 4 <= m; k += 4) {
            int r0 = __shfl(ids, k, 16),     r1 = __shfl(ids, k + 1, 16);
            int r2 = __shfl(ids, k + 2, 16), r3 = __shfl(ids, k + 3, 16);
            unsigned u0 = h32[(size_t)r0 * 16 + j];
            unsigned u1 = h32[(size_t)r1 * 16 + j];
            unsigned u2 = h32[(size_t)r2 * 16 + j];
            unsigned u3 = h32[(size_t)r3 * 16 + j];
            s0 += bfl(u0); s1 += bfh(u0);
            s0 += bfl(u1); s1 += bfh(u1);
            s0 += bfl(u2); s1 += bfh(u2);
            s0 += bfl(u3); s1 += bfh(u3);
        }
        for (; k < m; ++k) {
            int r = __shfl(ids, k, 16);
            unsigned uu = h32[(size_t)r * 16 + j];
            s0 += bfl(uu); s1 += bfh(uu);
        }
    }
    float dv = dis[c];
    float2 bb = ((const float2*)b2)[j];
    float2 o;
    o.x = bb.x - dv * s0;
    o.y = bb.y - dv * s1;
    ((float2*)out)[(size_t)c * 16 + j] = o;
}

extern "C" void kernel_launch(void* const* d_in, const int* in_sizes, int n_in,
                              void* d_out, int out_size, void* d_ws, size_t ws_size,
                              hipStream_t stream) {
    const float* x    = (const float*)d_in[0];
    const int*   ei   = (const int*)d_in[1];
    const int*   priv = (const int*)d_in[2];
    const float* W1   = (const float*)d_in[3];
    const float* b1   = (const float*)d_in[4];
    const float* W2   = (const float*)d_in[5];
    const float* b2   = (const float*)d_in[6];
    float* out = (float*)d_out;

    const int N = in_sizes[2];
    const int E = in_sizes[1] / 2;
    const int* row = ei;
    const int* col = ei + E;

    char* ws = (char*)d_ws;
    size_t off = 0;
    auto take = [&](size_t bytes) { char* p = ws + off; off = (off + bytes + 255) & ~(size_t)255; return p; };
    int*            hist     = (int*)           take((size_t)131072 * 4);
    int*            excl     = (int*)           take((size_t)131072 * 4);
    int*            bsum     = (int*)           take(512 * 4);
    unsigned short* W1b      = (unsigned short*)take((size_t)8192 * 2);
    unsigned short* W2b      = (unsigned short*)take((size_t)4096 * 2);
    unsigned*       cbuf     = (unsigned*)      take((size_t)E * 4);
    unsigned short* rbuf     = (unsigned short*)take((size_t)E * 2);
    float*          dis      = (float*)         take((size_t)N * 4);
    int*            cntC     = (int*)           take((size_t)N * 4);
    int*            colStart = (int*)           take((size_t)N * 4);
    unsigned short* eSrc     = (unsigned short*)take((size_t)E * 2);
    unsigned short* xt       = (unsigned short*)take((size_t)N * 64 * 2);
    unsigned short* agg1b    = (unsigned short*)take((size_t)N * 64 * 2);
    unsigned short* hps      = (unsigned short*)take((size_t)N * 32 * 2);
    (void)ws_size;

    const int chunk = (((E + 255) / 256) + 3) & ~3;   // multiple of 4 -> int4-aligned
    const int nbk = (N + 255) / 256;                  // node buckets (196 < 255)

    k_hist2   <<<256, 1024, 0, stream>>>(row, col, E, chunk, hist, W1, W2, W1b, W2b);
    k_scan_a  <<<512, 256, 0, stream>>>(hist, excl, bsum, 131072);
    k_part    <<<256, 1024, 0, stream>>>(row, col, E, chunk, excl, bsum, cbuf, rbuf);
    k_build   <<<2 * nbk, 256, 0, stream>>>(rbuf, cbuf, bsum, priv, x, N, E, nbk,
                                            dis, xt, cntC, colStart, eSrc);
    k_gather1 <<<((size_t)N * 32 + 255) / 256, 256, 0, stream>>>(xt, eSrc, colStart, cntC, dis, agg1b, N);
    k_mlp_mfma<<<(N + 63) / 64, 256, 0, stream>>>(agg1b, W1b, b1, W2b, dis, hps, N);
    k_gather2 <<<((size_t)N * 16 + 255) / 256, 256, 0, stream>>>(hps, eSrc, colStart, cntC, dis, b2, out, N);
}

// Round 9
// 144.237 us; speedup vs baseline: 1.2377x; 1.0154x over previous
//
#include <hip/hip_runtime.h>
#include <math.h>

// DP-GCN constants (EPS=1, ALPHA=0.5, DELTA=1):
//   transformed = ((e+1)*x - 1) * (1/(e-1)) + 0.5 = C1*x + C0
#define C1 2.163953413738653f
#define C0 -0.081976706869326f

// NOTE: assumes N <= 65536 so node ids fit u16 (N=50000 here).

typedef __attribute__((ext_vector_type(8))) short bf16x8;
typedef __attribute__((ext_vector_type(4))) float f32x4;

static __device__ __forceinline__ unsigned short f2bf(float f) {   // RTN-even
    unsigned b = __float_as_uint(f);
    return (unsigned short)((b + 0x7FFFu + ((b >> 16) & 1u)) >> 16);
}
static __device__ __forceinline__ float bf2f(unsigned short u) {
    return __uint_as_float((unsigned)u << 16);
}
// unpack a u32 holding two bf16 (little-endian: low half = even dim)
static __device__ __forceinline__ float bfl(unsigned u) { return __uint_as_float(u << 16); }
static __device__ __forceinline__ float bfh(unsigned u) { return __uint_as_float(u & 0xFFFF0000u); }

// ---- dual per-block histogram of col>>8 / row>>8; blocks 0/1 also convert W1/W2
// to bf16 swizzled into MFMA B-fragment order. hist[d*256+b] cols, [65536+d*256+b] rows.
// chunk is a multiple of 4 so &row[lo] is 16B-aligned for int4 loads.
__global__ __launch_bounds__(1024) void k_hist2(const int* __restrict__ row,
                                                const int* __restrict__ col, int E, int chunk,
                                                int* __restrict__ hist,
                                                const float* __restrict__ W1,
                                                const float* __restrict__ W2,
                                                unsigned short* __restrict__ W1b,
                                                unsigned short* __restrict__ W2b) {
    __shared__ int hc[256], hr[256];
    int t = threadIdx.x, b = blockIdx.x;
    if (t < 256) { hc[t] = 0; hr[t] = 0; }
    __syncthreads();
    int lo = b * chunk, hi = min(E, lo + chunk);
    int base = lo + t * 4;
    for (; base + 3 < hi; base += 4096) {
        int4 r4 = *(const int4*)&row[base];
        int4 c4 = *(const int4*)&col[base];
        atomicAdd(&hc[c4.x >> 8], 1); atomicAdd(&hc[c4.y >> 8], 1);
        atomicAdd(&hc[c4.z >> 8], 1); atomicAdd(&hc[c4.w >> 8], 1);
        atomicAdd(&hr[r4.x >> 8], 1); atomicAdd(&hr[r4.y >> 8], 1);
        atomicAdd(&hr[r4.z >> 8], 1); atomicAdd(&hr[r4.w >> 8], 1);
    }
    for (; base < hi; ++base) {
        atomicAdd(&hc[col[base] >> 8], 1);
        atomicAdd(&hr[row[base] >> 8], 1);
    }
    __syncthreads();
    if (t < 256) {
        hist[t * 256 + b] = hc[t];
        hist[65536 + t * 256 + b] = hr[t];
    }
    // B-fragment swizzle: frag element j of lane l for (ntile, ktile) holds
    // B[k = kt*32 + (l>>4)*8 + j][n = nt*16 + (l&15)], stored contiguously.
    if (b == 0) {
        for (int i = t; i < 8192; i += 1024) {           // W1: 8 nt x 2 kt
            int j = i & 7, l2 = (i >> 3) & 63, kt = (i >> 9) & 1, nt = i >> 10;
            int k = kt * 32 + (l2 >> 4) * 8 + j, n = nt * 16 + (l2 & 15);
            W1b[i] = f2bf(W1[k * 128 + n]);
        }
    } else if (b == 1) {
        for (int i = t; i < 4096; i += 1024) {           // W2: 2 nt x 4 kt
            int j = i & 7, l2 = (i >> 3) & 63, kt = (i >> 9) & 3, nt = i >> 11;
            int k = kt * 32 + (l2 >> 4) * 8 + j, n = nt * 16 + (l2 & 15);
            W2b[i] = f2bf(W2[k * 32 + n]);
        }
    }
}

// ---- level-1 exclusive scan: scan-block d = digit d's 256 per-block counts.
// excl[d*256+b] = within-digit prefix over blocks<b; bsum[d] = digit total.
__global__ void k_scan_a(const int* __restrict__ cnt, int* __restrict__ excl,
                         int* __restrict__ bsum, int n) {
    __shared__ int s[256];
    int idx = blockIdx.x * 256 + threadIdx.x;
    int v = (idx < n) ? cnt[idx] : 0;
    s[threadIdx.x] = v;
    __syncthreads();
    for (int off = 1; off < 256; off <<= 1) {
        int t = (threadIdx.x >= off) ? s[threadIdx.x - off] : 0;
        __syncthreads();
        s[threadIdx.x] += t;
        __syncthreads();
    }
    if (idx < n) excl[idx] = s[threadIdx.x] - v;
    if (threadIdx.x == 255) bsum[blockIdx.x] = s[255];
}

// ---- partition: digit bases from bsum (two concurrent 256-scans), then scatter.
// rbuf stores only the LOW byte of row: the digit region index supplies row>>8.
__global__ __launch_bounds__(1024) void k_part(const int* __restrict__ row,
                                               const int* __restrict__ col, int E, int chunk,
                                               const int* __restrict__ excl,
                                               const int* __restrict__ bsum,
                                               unsigned* __restrict__ cbuf,
                                               unsigned char* __restrict__ rbuf) {
    __shared__ int sc[512];
    __shared__ int offc[256], offr[256];
    int t = threadIdx.x, b = blockIdx.x;
    // concurrent exclusive scans: lanes 0-255 col digits, 256-511 row digits
    if (t < 512) sc[t] = bsum[t];
    __syncthreads();
    int half = t >> 8, d = t & 255;
    for (int off = 1; off < 256; off <<= 1) {
        int u = (t < 512 && d >= off) ? sc[half * 256 + d - off] : 0;
        __syncthreads();
        if (t < 512) sc[t] += u;
        __syncthreads();
    }
    if (t < 256) offc[t] = sc[t] - bsum[t] + excl[t * 256 + b];
    else if (t < 512) offr[d] = sc[t] - bsum[t] + excl[65536 + d * 256 + b];
    __syncthreads();
    int lo = b * chunk, hi = min(E, lo + chunk);
    int base = lo + t * 4;
    for (; base + 3 < hi; base += 4096) {
        int4 r4 = *(const int4*)&row[base];
        int4 c4 = *(const int4*)&col[base];
        int p0 = atomicAdd(&offc[c4.x >> 8], 1);
        cbuf[p0] = ((unsigned)c4.x << 16) | (unsigned)r4.x;
        int p1 = atomicAdd(&offc[c4.y >> 8], 1);
        cbuf[p1] = ((unsigned)c4.y << 16) | (unsigned)r4.y;
        int p2 = atomicAdd(&offc[c4.z >> 8], 1);
        cbuf[p2] = ((unsigned)c4.z << 16) | (unsigned)r4.z;
        int p3 = atomicAdd(&offc[c4.w >> 8], 1);
        cbuf[p3] = ((unsigned)c4.w << 16) | (unsigned)r4.w;
        int q0 = atomicAdd(&offr[r4.x >> 8], 1); rbuf[q0] = (unsigned char)r4.x;
        int q1 = atomicAdd(&offr[r4.y >> 8], 1); rbuf[q1] = (unsigned char)r4.y;
        int q2 = atomicAdd(&offr[r4.z >> 8], 1); rbuf[q2] = (unsigned char)r4.z;
        int q3 = atomicAdd(&offr[r4.w >> 8], 1); rbuf[q3] = (unsigned char)r4.w;
    }
    for (; base < hi; ++base) {
        int r = row[base], c = col[base];
        int pc = atomicAdd(&offc[c >> 8], 1);
        cbuf[pc] = ((unsigned)c << 16) | (unsigned)r;
        int pr = atomicAdd(&offr[r >> 8], 1);
        rbuf[pr] = (unsigned char)r;
    }
}

// ---- merged per-bucket build: blocks [0,nbk) deg->dis->xt; [nbk,2nbk) CSR ----
__global__ __launch_bounds__(256) void k_build(const unsigned char* __restrict__ rbuf,
                                               const unsigned* __restrict__ cbuf,
                                               const int* __restrict__ bsum,
                                               const int* __restrict__ priv,
                                               const float* __restrict__ x, int N, int E, int nbk,
                                               float* __restrict__ dis,
                                               unsigned short* __restrict__ xt,
                                               int* __restrict__ cntC, int* __restrict__ colStart,
                                               unsigned short* __restrict__ eSrc) {
    __shared__ int s1[256], s2[256], s3[256];
    int t = threadIdx.x;
    if ((int)blockIdx.x < nbk) {
        // ---- deg -> dis -> bf16 xt ----
        int b = blockIdx.x;
        s1[t] = (t < b) ? bsum[256 + t] : 0;   // prefix of row-digit totals
        __syncthreads();
        for (int off = 128; off > 0; off >>= 1) {
            if (t < off) s1[t] += s1[t + off];
            __syncthreads();
        }
        int rs = s1[0];
        int re = rs + bsum[256 + b];
        __syncthreads();
        s1[t] = 0;
        __syncthreads();
        for (int i = rs + t; i < re; i += 256) atomicAdd(&s1[rbuf[i]], 1);
        __syncthreads();
        int node = b * 256 + t;
        float dv = rsqrtf((float)(s1[t] + 1));       // +1 self loop
        if (node < N) {
            dis[node] = dv;
            s2[t] = __float_as_int(dv);
            s3[t] = priv[node];
        } else { s2[t] = 0; s3[t] = 0; }
        __syncthreads();
        int base = b * 256;
        for (int i = t; i < 256 * 16; i += 256) {     // 16 float4 per node
            int ln = i >> 4;
            int n2 = base + ln;
            if (n2 >= N) continue;
            float d2 = __int_as_float(s2[ln]);
            int p = s3[ln];
            float4 v = ((const float4*)x)[(size_t)n2 * 16 + (i & 15)];
            float4 tr;
            tr.x = p ? fmaf(C1, v.x, C0) : v.x;
            tr.y = p ? fmaf(C1, v.y, C0) : v.y;
            tr.z = p ? fmaf(C1, v.z, C0) : v.z;
            tr.w = p ? fmaf(C1, v.w, C0) : v.w;
            ushort4 o;
            o.x = f2bf(d2 * tr.x); o.y = f2bf(d2 * tr.y);
            o.z = f2bf(d2 * tr.z); o.w = f2bf(d2 * tr.w);
            ((ushort4*)xt)[(size_t)n2 * 16 + (i & 15)] = o;
        }
    } else {
        // ---- CSR: cntC/colStart + eSrc[pos] = row (u16) ----
        int b = blockIdx.x - nbk;
        s1[t] = (t < b) ? bsum[t] : 0;          // prefix of col-digit totals
        __syncthreads();
        for (int off = 128; off > 0; off >>= 1) {
            if (t < off) s1[t] += s1[t + off];
            __syncthreads();
        }
        int cs = s1[0];
        int ce = cs + bsum[b];
        __syncthreads();
        s1[t] = 0; s3[t] = 0;
        __syncthreads();
        for (int i = cs + t; i < ce; i += 256) atomicAdd(&s1[(cbuf[i] >> 16) & 255], 1);
        __syncthreads();
        int v = s1[t];
        s2[t] = v;
        __syncthreads();
        for (int off = 1; off < 256; off <<= 1) {
            int u = (t >= off) ? s2[t - off] : 0;
            __syncthreads();
            s2[t] += u;
            __syncthreads();
        }
        int excl = s2[t] - v;
        int c = b * 256 + t;
        if (c < N) { cntC[c] = v; colStart[c] = cs + excl; }
        __syncthreads();
        s2[t] = excl;
        __syncthreads();
        for (int i = cs + t; i < ce; i += 256) {
            unsigned e = cbuf[i];
            int d = (e >> 16) & 255;
            int pos = cs + s2[d] + atomicAdd(&s3[d], 1);
            eSrc[pos] = (unsigned short)(e & 0xFFFFu);
        }
    }
}

// conv1 by gather: agg1b[c] = bf16( dis_c * (xt_c + sum_r xt_r) )
// u64 lanes: 16 lanes per column (4 bf16 dims each), 4 columns per wave, 8x unroll.
__global__ __launch_bounds__(256) void k_gather1(const unsigned short* __restrict__ xt,
                                                 const unsigned short* __restrict__ eSrc,
                                                 const int* __restrict__ colStart,
                                                 const int* __restrict__ cntC,
                                                 const float* __restrict__ dis,
                                                 unsigned short* __restrict__ agg1b, int N) {
    int t = blockIdx.x * blockDim.x + threadIdx.x;
    int c = t >> 4, j = t & 15;
    if (c >= N) return;
    const uint2* x64 = (const uint2*)xt;     // node row = 16 uint2 (64 bf16)
    uint2 u = x64[(size_t)c * 16 + j];       // self loop (dims 4j..4j+3)
    float s0 = bfl(u.x), s1 = bfh(u.x), s2 = bfl(u.y), s3 = bfh(u.y);
    int start = colStart[c], cnt = cntC[c];
    for (int base = 0; base < cnt; base += 16) {
        int m = min(cnt - base, 16);
        int ids = (j < m) ? (int)eSrc[start + base + j] : 0;
        int k = 0;
        for (; k + 8 <= m; k += 8) {
            int r0 = __shfl(ids, k, 16),     r1 = __shfl(ids, k + 1, 16);
            int r2 = __shfl(ids, k + 2, 16), r3 = __shfl(ids, k + 3, 16);
            int r4 = __shfl(ids, k + 4, 16), r5 = __shfl(ids, k + 5, 16);
            int r6 = __shfl(ids, k + 6, 16), r7 = __shfl(ids, k + 7, 16);
            uint2 u0 = x64[(size_t)r0 * 16 + j];
            uint2 u1 = x64[(size_t)r1 * 16 + j];
            uint2 u2 = x64[(size_t)r2 * 16 + j];
            uint2 u3 = x64[(size_t)r3 * 16 + j];
            uint2 u4 = x64[(size_t)r4 * 16 + j];
            uint2 u5 = x64[(size_t)r5 * 16 + j];
            uint2 u6 = x64[(size_t)r6 * 16 + j];
            uint2 u7 = x64[(size_t)r7 * 16 + j];
            s0 += bfl(u0.x); s1 += bfh(u0.x); s2 += bfl(u0.y); s3 += bfh(u0.y);
            s0 += bfl(u1.x); s1 += bfh(u1.x); s2 += bfl(u1.y); s3 += bfh(u1.y);
            s0 += bfl(u2.x); s1 += bfh(u2.x); s2 += bfl(u2.y); s3 += bfh(u2.y);
            s0 += bfl(u3.x); s1 += bfh(u3.x); s2 += bfl(u3.y); s3 += bfh(u3.y);
            s0 += bfl(u4.x); s1 += bfh(u4.x); s2 += bfl(u4.y); s3 += bfh(u4.y);
            s0 += bfl(u5.x); s1 += bfh(u5.x); s2 += bfl(u5.y); s3 += bfh(u5.y);
            s0 += bfl(u6.x); s1 += bfh(u6.x); s2 += bfl(u6.y); s3 += bfh(u6.y);
            s0 += bfl(u7.x); s1 += bfh(u7.x); s2 += bfl(u7.y); s3 += bfh(u7.y);
        }
        for (; k + 4 <= m; k += 4) {
            int r0 = __shfl(ids, k, 16),     r1 = __shfl(ids, k + 1, 16);
            int r2 = __shfl(ids, k + 2, 16), r3 = __shfl(ids, k + 3, 16);
            uint2 u0 = x64[(size_t)r0 * 16 + j];
            uint2 u1 = x64[(size_t)r1 * 16 + j];
            uint2 u2 = x64[(size_t)r2 * 16 + j];
            uint2 u3 = x64[(size_t)r3 * 16 + j];
            s0 += bfl(u0.x); s1 += bfh(u0.x); s2 += bfl(u0.y); s3 += bfh(u0.y);
            s0 += bfl(u1.x); s1 += bfh(u1.x); s2 += bfl(u1.y); s3 += bfh(u1.y);
            s0 += bfl(u2.x); s1 += bfh(u2.x); s2 += bfl(u2.y); s3 += bfh(u2.y);
            s0 += bfl(u3.x); s1 += bfh(u3.x); s2 += bfl(u3.y); s3 += bfh(u3.y);
        }
        for (; k < m; ++k) {
            int r = __shfl(ids, k, 16);
            uint2 uu = x64[(size_t)r * 16 + j];
            s0 += bfl(uu.x); s1 += bfh(uu.x); s2 += bfl(uu.y); s3 += bfh(uu.y);
        }
    }
    float dv = dis[c];
    uint2 o;
    o.x = ((unsigned)f2bf(dv * s1) << 16) | (unsigned)f2bf(dv * s0);
    o.y = ((unsigned)f2bf(dv * s3) << 16) | (unsigned)f2bf(dv * s2);
    ((uint2*)agg1b)[(size_t)c * 16 + j] = o;
}

// ---- MFMA MLP: hps = bf16(dis * (relu(A@W1+b1)@W2)); 64-node tile, 4 waves ----
__global__ __launch_bounds__(256) void k_mlp_mfma(const unsigned short* __restrict__ agg1b,
                                                  const unsigned short* __restrict__ W1b,
                                                  const float* __restrict__ b1,
                                                  const unsigned short* __restrict__ W2b,
                                                  const float* __restrict__ dis,
                                                  unsigned short* __restrict__ hps, int N) {
    __shared__ unsigned short hidA[4][16 * 136];   // per-wave 16 x 128 (+8 pad)
    const int t = threadIdx.x;
    const int w = t >> 6, l = t & 63;
    const int q = l >> 4, lm = l & 15;
    const int rowbase = blockIdx.x * 64 + w * 16;

    bf16x8 a0, a1;
    {
        int node = rowbase + lm;
        if (node >= N) node = N - 1;
        const bf16x8* pa = (const bf16x8*)(agg1b + (size_t)node * 64);
        a0 = pa[q];
        a1 = pa[4 + q];
    }
    float dvals[4];
    #pragma unroll
    for (int r = 0; r < 4; ++r) {
        int node = rowbase + q * 4 + r;
        dvals[r] = (node < N) ? dis[node] : 0.f;
    }

    const bf16x8* w1f = (const bf16x8*)W1b;
    #pragma unroll
    for (int nt = 0; nt < 8; ++nt) {
        float bv = b1[nt * 16 + lm];
        f32x4 acc = {bv, bv, bv, bv};
        acc = __builtin_amdgcn_mfma_f32_16x16x32_bf16(a0, w1f[(nt * 2 + 0) * 64 + l], acc, 0, 0, 0);
        acc = __builtin_amdgcn_mfma_f32_16x16x32_bf16(a1, w1f[(nt * 2 + 1) * 64 + l], acc, 0, 0, 0);
        #pragma unroll
        for (int r = 0; r < 4; ++r)
            hidA[w][(q * 4 + r) * 136 + nt * 16 + lm] = f2bf(fmaxf(acc[r], 0.f));
    }
    __syncthreads();

    bf16x8 ha[4];
    #pragma unroll
    for (int kt = 0; kt < 4; ++kt)
        ha[kt] = *(const bf16x8*)&hidA[w][lm * 136 + kt * 32 + q * 8];

    const bf16x8* w2f = (const bf16x8*)W2b;
    #pragma unroll
    for (int nt = 0; nt < 2; ++nt) {
        f32x4 acc = {0.f, 0.f, 0.f, 0.f};
        #pragma unroll
        for (int kt = 0; kt < 4; ++kt)
            acc = __builtin_amdgcn_mfma_f32_16x16x32_bf16(ha[kt], w2f[(nt * 4 + kt) * 64 + l], acc, 0, 0, 0);
        #pragma unroll
        for (int r = 0; r < 4; ++r) {
            int node = rowbase + q * 4 + r;
            if (node < N)
                hps[(size_t)node * 32 + nt * 16 + lm] = f2bf(acc[r] * dvals[r]);
        }
    }
}

// conv2 by gather: out[c] = b2 - dis_c * (hps_c + sum_r hps_r)
// u64 lanes: 8 lanes per column (4 bf16 dims each), 8 columns per wave, 8x unroll.
__global__ __launch_bounds__(256) void k_gather2(const unsigned short* __restrict__ hps,
                                                 const unsigned short* __restrict__ eSrc,
                                                 const int* __restrict__ colStart,
                                                 const int* __restrict__ cntC,
                                                 const float* __restrict__ dis,
                                                 const float* __restrict__ b2,
                                                 float* __restrict__ out, int N) {
    int t = blockIdx.x * blockDim.x + threadIdx.x;
    int c = t >> 3, j = t & 7;
    if (c >= N) return;
    const uint2* h64 = (const uint2*)hps;    // node row = 8 uint2 (32 bf16)
    uint2 u = h64[(size_t)c * 8 + j];        // self loop (dims 4j..4j+3)
    float s0 = bfl(u.x), s1 = bfh(u.x), s2 = bfl(u.y), s3 = bfh(u.y);
    int start = colStart[c], cnt = cntC[c];
    for (int base = 0; base < cnt; base += 8) {
        int m = min(cnt - base, 8);
        int ids = (j < m) ? (int)eSrc[start + base + j] : 0;
        int k = 0;
        for (; k + 8 <= m; k += 8) {
            int r0 = __shfl(ids, k, 8),     r1 = __shfl(ids, k + 1, 8);
            int r2 = __shfl(ids, k + 2, 8), r3 = __shfl(ids, k + 3, 8);
            int r4 = __shfl(ids, k + 4, 8), r5 = __shfl(ids, k + 5, 8);
            int r6 = __shfl(ids, k + 6, 8), r7 = __shfl(ids, k + 7, 8);
            uint2 u0 = h64[(size_t)r0 * 8 + j];
            uint2 u1 = h64[(size_t)r1 * 8 + j];
            uint2 u2 = h64[(size_t)r2 * 8 + j];
            uint2 u3 = h64[(size_t)r3 * 8 + j];
            uint2 u4 = h64[(size_t)r4 * 8 + j];
            uint2 u5 = h64[(size_t)r5 * 8 + j];
            uint2 u6 = h64[(size_t)r6 * 8 + j];
            uint2 u7 = h64[(size_t)r7 * 8 + j];
            s0 += bfl(u0.x); s1 += bfh(u0.x); s2 += bfl(u0.y); s3 += bfh(u0.y);
            s0 += bfl(u1.x); s1 += bfh(u1.x); s2 += bfl(u1.y); s3 += bfh(u1.y);
            s0 += bfl(u2.x); s1 += bfh(u2.x); s2 += bfl(u2.y); s3 += bfh(u2.y);
            s0 += bfl(u3.x); s1 += bfh(u3.x); s2 += bfl(u3.y); s3 += bfh(u3.y);
            s0 += bfl(u4.x); s1 += bfh(u4.x); s2 += bfl(u4.y); s3 += bfh(u4.y);
            s0 += bfl(u5.x); s1 += bfh(u5.x); s2 += bfl(u5.y); s3 += bfh(u5.y);
            s0 += bfl(u6.x); s1 += bfh(u6.x); s2 += bfl(u6.y); s3 += bfh(u6.y);
            s0 += bfl(u7.x); s1 += bfh(u7.x); s2 += bfl(u7.y); s3 += bfh(u7.y);
        }
        for (; k + 4 <= m; k += 4) {
            int r0 = __shfl(ids, k, 8),     r1 = __shfl(ids, k + 1, 8);
            int r2 = __shfl(ids, k + 2, 8), r3 = __shfl(ids, k + 3, 8);
            uint2 u0 = h64[(size_t)r0 * 8 + j];
            uint2 u1 = h64[(size_t)r1 * 8 + j];
            uint2 u2 = h64[(size_t)r2 * 8 + j];
            uint2 u3 = h64[(size_t)r3 * 8 + j];
            s0 += bfl(u0.x); s1 += bfh(u0.x); s2 += bfl(u0.y); s3 += bfh(u0.y);
            s0 += bfl(u1.x); s1 += bfh(u1.x); s2 += bfl(u1.y); s3 += bfh(u1.y);
            s0 += bfl(u2.x); s1 += bfh(u2.x); s2 += bfl(u2.y); s3 += bfh(u2.y);
            s0 += bfl(u3.x); s1 += bfh(u3.x); s2 += bfl(u3.y); s3 += bfh(u3.y);
        }
        for (; k < m; ++k) {
            int r = __shfl(ids, k, 8);
            uint2 uu = h64[(size_t)r * 8 + j];
            s0 += bfl(uu.x); s1 += bfh(uu.x); s2 += bfl(uu.y); s3 += bfh(uu.y);
        }
    }
    float dv = dis[c];
    float4 bb = ((const float4*)b2)[j];
    float4 o;
    o.x = bb.x - dv * s0;
    o.y = bb.y - dv * s1;
    o.z = bb.z - dv * s2;
    o.w = bb.w - dv * s3;
    ((float4*)out)[(size_t)c * 8 + j] = o;
}

extern "C" void kernel_launch(void* const* d_in, const int* in_sizes, int n_in,
                              void* d_out, int out_size, void* d_ws, size_t ws_size,
                              hipStream_t stream) {
    const float* x    = (const float*)d_in[0];
    const int*   ei   = (const int*)d_in[1];
    const int*   priv = (const int*)d_in[2];
    const float* W1   = (const float*)d_in[3];
    const float* b1   = (const float*)d_in[4];
    const float* W2   = (const float*)d_in[5];
    const float* b2   = (const float*)d_in[6];
    float* out = (float*)d_out;

    const int N = in_sizes[2];
    const int E = in_sizes[1] / 2;
    const int* row = ei;
    const int* col = ei + E;

    char* ws = (char*)d_ws;
    size_t off = 0;
    auto take = [&](size_t bytes) { char* p = ws + off; off = (off + bytes + 255) & ~(size_t)255; return p; };
    int*            hist     = (int*)           take((size_t)131072 * 4);
    int*            excl     = (int*)           take((size_t)131072 * 4);
    int*            bsum     = (int*)           take(512 * 4);
    unsigned short* W1b      = (unsigned short*)take((size_t)8192 * 2);
    unsigned short* W2b      = (unsigned short*)take((size_t)4096 * 2);
    unsigned*       cbuf     = (unsigned*)      take((size_t)E * 4);
    unsigned char*  rbuf     = (unsigned char*) take((size_t)E);
    float*          dis      = (float*)         take((size_t)N * 4);
    int*            cntC     = (int*)           take((size_t)N * 4);
    int*            colStart = (int*)           take((size_t)N * 4);
    unsigned short* eSrc     = (unsigned short*)take((size_t)E * 2);
    unsigned short* xt       = (unsigned short*)take((size_t)N * 64 * 2);
    unsigned short* agg1b    = (unsigned short*)take((size_t)N * 64 * 2);
    unsigned short* hps      = (unsigned short*)take((size_t)N * 32 * 2);
    (void)ws_size;

    const int chunk = (((E + 255) / 256) + 3) & ~3;   // multiple of 4 -> int4-aligned
    const int nbk = (N + 255) / 256;                  // node buckets (196 < 255)

    k_hist2   <<<256, 1024, 0, stream>>>(row, col, E, chunk, hist, W1, W2, W1b, W2b);
    k_scan_a  <<<512, 256, 0, stream>>>(hist, excl, bsum, 131072);
    k_part    <<<256, 1024, 0, stream>>>(row, col, E, chunk, excl, bsum, cbuf, rbuf);
    k_build   <<<2 * nbk, 256, 0, stream>>>(rbuf, cbuf, bsum, priv, x, N, E, nbk,
                                            dis, xt, cntC, colStart, eSrc);
    k_gather1 <<<((size_t)N * 16 + 255) / 256, 256, 0, stream>>>(xt, eSrc, colStart, cntC, dis, agg1b, N);
    k_mlp_mfma<<<(N + 63) / 64, 256, 0, stream>>>(agg1b, W1b, b1, W2b, dis, hps, N);
    k_gather2 <<<((size_t)N * 8 + 255) / 256, 256, 0, stream>>>(hps, eSrc, colStart, cntC, dis, b2, out, N);
}